// Round 3
// baseline (208.626 us; speedup 1.0000x reference)
//
#include <hip/hip_runtime.h>
#include <hip/hip_bf16.h>

#define H_ 128
#define W_ 128
#define B_ 8
#define CIN_ 64
#define COUT_ 64

typedef __attribute__((ext_vector_type(8))) short bf16x8;
typedef __attribute__((ext_vector_type(4))) float f32x4;
typedef __attribute__((ext_vector_type(4))) unsigned int u32x4;

static __device__ __forceinline__ unsigned short f2bf(float f) {
  union { float f; unsigned int u; } a; a.f = f;
  unsigned int u = a.u;
  return (unsigned short)((u + 0x7fffu + ((u >> 16) & 1u)) >> 16);  // RNE, finite
}

static __device__ __forceinline__ unsigned int cvt_pk_bf16(float lo, float hi) {
  unsigned int r;
  asm("v_cvt_pk_bf16_f32 %0, %1, %2" : "=v"(r) : "v"(lo), "v"(hi));
  return r;
}

// unpack bf16x8 (4 u32 words) -> 8 f32: 2 VALU per word
static __device__ __forceinline__ void unpack8(const bf16x8& q, float g[8]) {
  union { bf16x8 v; unsigned int w[4]; } u; u.v = q;
#pragma unroll
  for (int j = 0; j < 4; ++j) {
    g[2 * j]     = __uint_as_float(u.w[j] << 16);
    g[2 * j + 1] = __uint_as_float(u.w[j] & 0xffff0000u);
  }
}

// ---------------- prep: transpose both weight tensors to bf16 ----------------
// dwt: (o,c,k) f32 -> [k][o(64)][c(64)] bf16      (36864 elems)
// owt: (18,c,t) f32 -> [t][om(32, zero-pad)][c(64)] bf16  (18432 elems)
__global__ __launch_bounds__(256) void prep_w(const float* __restrict__ dw,
    const float* __restrict__ ow, unsigned short* __restrict__ dwt,
    unsigned short* __restrict__ owt) {
  int id = blockIdx.x * 256 + threadIdx.x;
  if (id < 36864) {
    int c = id & 63, o = (id >> 6) & 63, k = id >> 12;
    dwt[id] = f2bf(dw[(o * 64 + c) * 9 + k]);
  } else if (id < 36864 + 18432) {
    int j = id - 36864;
    int c = j & 63, om = (j >> 6) & 31, t = j >> 11;
    owt[j] = f2bf(om < 18 ? ow[(om * 64 + c) * 9 + t] : 0.f);
  }
}

// ---------------- fused deformable block ----------------
// grid = B*16*16 (8x8 pixel tiles), block 256 = 4 waves.
// Wave wv owns pixels [wv*16, wv*16+16) and computes ALL 64 couts for them
// (4 M-tiles). B-fragments built per-lane in registers -> no barriers in tap loop.
// x-tile in LDS: rows [ty-3,ty+11] (15) x cols [tx-4,tx+11] (16), [pt][c] bf16,
// 16B-slot XOR swizzle (c8 ^ (pt&7)).

__device__ __forceinline__ void corner8(const float* __restrict__ x,
    const unsigned short* __restrict__ ldsx, int b, int iy, int ix,
    int oy, int ox, int c8, float g[8]) {
  int ly = iy - oy, lx = ix - ox;
  if ((unsigned)ly < 15u && (unsigned)lx < 16u) {
    int pt = (ly << 4) | lx;
    bf16x8 q = *(const bf16x8*)&ldsx[(pt << 6) | ((c8 ^ (pt & 7)) << 3)];
    unpack8(q, g);
  } else if ((unsigned)iy < (unsigned)H_ && (unsigned)ix < (unsigned)W_) {
#pragma unroll
    for (int ci = 0; ci < 8; ++ci)
      g[ci] = x[((b * CIN_ + (c8 << 3) + ci) * H_ + iy) * W_ + ix];
  } else {
#pragma unroll
    for (int ci = 0; ci < 8; ++ci) g[ci] = 0.f;
  }
}

__global__ __launch_bounds__(256, 4) void deform_main(const float* __restrict__ x,
    const unsigned short* __restrict__ owt, const float* __restrict__ ob,
    const unsigned short* __restrict__ dwt, const float* __restrict__ db,
    float* __restrict__ out) {
  __shared__ unsigned short ldsx[240 * 64];   // 30 KB
  __shared__ float offs_lds[64][18];          // 4.5 KB

  const int tid = threadIdx.x;
  const int blk = blockIdx.x;
  const int b = blk >> 8;
  const int ty = ((blk >> 4) & 15) << 3;
  const int tx = (blk & 15) << 3;
  const int oy = ty - 3, ox = tx - 4;
  const int lane = tid & 63;
  const int wv = tid >> 6;
  const int pl = lane & 15;
  const int kgrp = lane >> 4;                // 0..3 (K-slice group)
  const int pwl = (wv << 4) | pl;            // this lane's pixel 0..63
  const int pyy = ty + (pwl >> 3), pxx = tx + (pwl & 7);

  // ---- phase 0: stage x tile, one (pt, all c) per thread ----
  {
    int pt = tid;                    // 0..255, valid < 240
    if (pt < 240) {
      int gy = oy + (pt >> 4), gx = ox + (pt & 15);
      bool ok = ((unsigned)gy < (unsigned)H_) && ((unsigned)gx < (unsigned)W_);
      int base = ((b * CIN_) * H_ + gy) * W_ + gx;
#pragma unroll
      for (int c8 = 0; c8 < 8; ++c8) {
        float v[8];
#pragma unroll
        for (int ci = 0; ci < 8; ++ci)
          v[ci] = ok ? x[base + ((c8 << 3) + ci) * (H_ * W_)] : 0.f;
        u32x4 sv;
#pragma unroll
        for (int j = 0; j < 4; ++j) sv[j] = cvt_pk_bf16(v[2 * j], v[2 * j + 1]);
        *(u32x4*)&ldsx[(pt << 6) | ((c8 ^ (pt & 7)) << 3)] = sv;
      }
    }
  }
  __syncthreads();

  // ---- phase 1: offset conv via MFMA; wave wv does its own 16 pixels ----
  {
    f32x4 aoff0 = (f32x4){0.f, 0.f, 0.f, 0.f};
    f32x4 aoff1 = (f32x4){0.f, 0.f, 0.f, 0.f};
#pragma unroll
    for (int t = 0; t < 9; ++t) {
      const int ly = (pwl >> 3) + (t / 3) - 1 + 3;   // [2,11]
      const int lx = (pwl & 7) + (t % 3) - 1 + 4;    // [3,12]
      const int pt = (ly << 4) | lx;
#pragma unroll
      for (int hf = 0; hf < 2; ++hf) {
        const int c8 = (hf << 2) | kgrp;
        bf16x8 bfr = *(const bf16x8*)&ldsx[(pt << 6) | ((c8 ^ (pt & 7)) << 3)];
        bf16x8 a0 = *(const bf16x8*)&owt[(((t << 5) | pl) << 6) | (c8 << 3)];
        bf16x8 a1 = *(const bf16x8*)&owt[(((t << 5) | 16 | pl) << 6) | (c8 << 3)];
        aoff0 = __builtin_amdgcn_mfma_f32_16x16x32_bf16(a0, bfr, aoff0, 0, 0, 0);
        aoff1 = __builtin_amdgcn_mfma_f32_16x16x32_bf16(a1, bfr, aoff1, 0, 0, 0);
      }
    }
#pragma unroll
    for (int j = 0; j < 4; ++j) {
      int o = (kgrp << 2) + j;
      offs_lds[pwl][o] = aoff0[j] + ob[o];
      int o1 = 16 + o;
      if (o1 < 18) offs_lds[pwl][o1] = aoff1[j] + ob[o1];
    }
  }
  __syncthreads();

  // ---- phase 2: tap loop, barrier-free; B-frags in registers ----
  f32x4 acc[4];
#pragma unroll
  for (int mt = 0; mt < 4; ++mt) acc[mt] = (f32x4){0.f, 0.f, 0.f, 0.f};

#pragma unroll
  for (int k = 0; k < 9; ++k) {
    float dy = offs_lds[pwl][2 * k];
    float dx = offs_lds[pwl][2 * k + 1];
    float py = (float)(pyy + (k / 3) - 1) + dy;
    float px = (float)(pxx + (k % 3) - 1) + dx;
    float fy = floorf(py), fx = floorf(px);
    int iy = (int)fy, ix = (int)fx;
    float wy = py - fy, wx = px - fx;
    float wy1 = 1.f - wy, wx1 = 1.f - wx;
    float w00 = wy1 * wx1, w01 = wy1 * wx, w10 = wy * wx1, w11 = wy * wx;

#pragma unroll
    for (int hf = 0; hf < 2; ++hf) {
      const int c8 = (hf << 2) | kgrp;
      float g00[8], g01[8], g10[8], g11[8];
      corner8(x, ldsx, b, iy,     ix,     oy, ox, c8, g00);
      corner8(x, ldsx, b, iy,     ix + 1, oy, ox, c8, g01);
      corner8(x, ldsx, b, iy + 1, ix,     oy, ox, c8, g10);
      corner8(x, ldsx, b, iy + 1, ix + 1, oy, ox, c8, g11);
      union { bf16x8 v; u32x4 w; } bfrag;
#pragma unroll
      for (int j = 0; j < 4; ++j) {
        float v0 = fmaf(g11[2 * j], w11, fmaf(g10[2 * j], w10,
                   fmaf(g01[2 * j], w01, g00[2 * j] * w00)));
        float v1 = fmaf(g11[2 * j + 1], w11, fmaf(g10[2 * j + 1], w10,
                   fmaf(g01[2 * j + 1], w01, g00[2 * j + 1] * w00)));
        bfrag.w[j] = cvt_pk_bf16(v0, v1);
      }
#pragma unroll
      for (int mt = 0; mt < 4; ++mt) {
        bf16x8 af = *(const bf16x8*)&dwt[(k << 12) + (((mt << 4) | pl) << 6)
                                         + (hf << 5) + (kgrp << 3)];
        acc[mt] = __builtin_amdgcn_mfma_f32_16x16x32_bf16(af, bfrag.v, acc[mt], 0, 0, 0);
      }
    }
  }

  // ---- epilogue: D col=lane&15 (pixel), row=(lane>>4)*4+j (cout in M-tile) ----
#pragma unroll
  for (int mt = 0; mt < 4; ++mt) {
#pragma unroll
    for (int j = 0; j < 4; ++j) {
      int o = (mt << 4) | (kgrp << 2) | j;
      float v = acc[mt][j] + db[o];
      out[((b * COUT_ + o) * H_ + pyy) * W_ + pxx] = v > 0.f ? v : 0.f;
    }
  }
}

extern "C" void kernel_launch(void* const* d_in, const int* in_sizes, int n_in,
                              void* d_out, int out_size, void* d_ws, size_t ws_size,
                              hipStream_t stream) {
  const float* x  = (const float*)d_in[0];
  const float* ow = (const float*)d_in[1];
  const float* ob = (const float*)d_in[2];
  const float* dw = (const float*)d_in[3];
  const float* db = (const float*)d_in[4];
  float* out = (float*)d_out;

  unsigned short* dwt = (unsigned short*)d_ws;                    // 36864 bf16
  unsigned short* owt = (unsigned short*)((char*)d_ws + 73728);   // 18432 bf16

  hipLaunchKernelGGL(prep_w, dim3(216), dim3(256), 0, stream, dw, ow, dwt, owt);
  hipLaunchKernelGGL(deform_main, dim3(2048), dim3(256), 0, stream,
                     x, owt, ob, dwt, db, out);
}

// Round 4
// 190.618 us; speedup vs baseline: 1.0945x; 1.0945x over previous
//
#include <hip/hip_runtime.h>
#include <hip/hip_bf16.h>

#define H_ 128
#define W_ 128
#define B_ 8
#define CIN_ 64
#define COUT_ 64

typedef __attribute__((ext_vector_type(8))) short bf16x8;
typedef __attribute__((ext_vector_type(4))) float f32x4;
typedef __attribute__((ext_vector_type(4))) unsigned int u32x4;

static __device__ __forceinline__ unsigned short f2bf(float f) {
  union { float f; unsigned int u; } a; a.f = f;
  unsigned int u = a.u;
  return (unsigned short)((u + 0x7fffu + ((u >> 16) & 1u)) >> 16);  // RNE, finite
}

static __device__ __forceinline__ unsigned int cvt_pk_bf16(float lo, float hi) {
  unsigned int r;
  asm("v_cvt_pk_bf16_f32 %0, %1, %2" : "=v"(r) : "v"(lo), "v"(hi));
  return r;
}

// ---------------- prep: transpose both weight tensors to bf16 ----------------
// dwt: (o,c,k) f32 -> [k][o(64)][c(64)] bf16      (36864 elems)
// owt: (18,c,t) f32 -> [t][om(32, zero-pad)][c(64)] bf16  (18432 elems)
__global__ __launch_bounds__(256) void prep_w(const float* __restrict__ dw,
    const float* __restrict__ ow, unsigned short* __restrict__ dwt,
    unsigned short* __restrict__ owt) {
  int id = blockIdx.x * 256 + threadIdx.x;
  if (id < 36864) {
    int c = id & 63, o = (id >> 6) & 63, k = id >> 12;
    dwt[id] = f2bf(dw[(o * 64 + c) * 9 + k]);
  } else if (id < 36864 + 18432) {
    int j = id - 36864;
    int c = j & 63, om = (j >> 6) & 31, t = j >> 11;
    owt[j] = f2bf(om < 18 ? ow[(om * 64 + c) * 9 + t] : 0.f);
  }
}

// ---------------- fused deformable block ----------------
// grid = B*16*16 (8x8 pixel tiles), block 256 = 4 waves.
// Wave wv owns pixels [wv*16, wv*16+16), computes all 64 couts (4 M-tiles).
// x-tile in LDS: rows [ty-3,ty+11] (15) x cols [tx-4,tx+11] (16), [pt][c] bf16,
// 16B-slot XOR swizzle (c8 ^ (pt&7)). ONE barrier; tap loop branch-free.

__global__ __launch_bounds__(256, 4) void deform_main(const float* __restrict__ x,
    const unsigned short* __restrict__ owt, const float* __restrict__ ob,
    const unsigned short* __restrict__ dwt, const float* __restrict__ db,
    float* __restrict__ out) {
  __shared__ unsigned short ldsx[240 * 64];   // 30 KB

  const int tid = threadIdx.x;
  // XCD swizzle: orig blk i runs on XCD i%8; give XCD x the contiguous range
  // [x*256, (x+1)*256) = exactly batch image b=x -> halo reuse stays in-XCD L2.
  const int blk = ((blockIdx.x & 7) << 8) | (blockIdx.x >> 3);
  const int b = blk >> 8;
  const int ty = ((blk >> 4) & 15) << 3;
  const int tx = (blk & 15) << 3;
  const int oy = ty - 3, ox = tx - 4;
  const int lane = tid & 63;
  const int wv = tid >> 6;
  const int pl = lane & 15;
  const int kgrp = lane >> 4;                // 0..3 (K-slice group)
  const int pwl = (wv << 4) | pl;            // this lane's pixel 0..63
  const int pyy = ty + (pwl >> 3), pxx = tx + (pwl & 7);

  // ---- phase 0: stage x tile, one (pt, all c) per thread ----
  {
    int pt = tid;                    // 0..255, valid < 240
    if (pt < 240) {
      int gy = oy + (pt >> 4), gx = ox + (pt & 15);
      bool ok = ((unsigned)gy < (unsigned)H_) && ((unsigned)gx < (unsigned)W_);
      int base = ((b * CIN_) * H_ + gy) * W_ + gx;
#pragma unroll
      for (int c8 = 0; c8 < 8; ++c8) {
        float v[8];
#pragma unroll
        for (int ci = 0; ci < 8; ++ci)
          v[ci] = ok ? x[base + ((c8 << 3) + ci) * (H_ * W_)] : 0.f;
        u32x4 sv;
#pragma unroll
        for (int j = 0; j < 4; ++j) sv[j] = cvt_pk_bf16(v[2 * j], v[2 * j + 1]);
        *(u32x4*)&ldsx[(pt << 6) | ((c8 ^ (pt & 7)) << 3)] = sv;
      }
    }
  }
  __syncthreads();

  // ---- phase 1: offset conv via MFMA; results stay in registers ----
  float ow0, ow1, ow2, ow3, owA, owB;   // lane-owned offsets o=4*kgrp+j, 16, 17
  {
    f32x4 aoff0 = (f32x4){0.f, 0.f, 0.f, 0.f};
    f32x4 aoff1 = (f32x4){0.f, 0.f, 0.f, 0.f};
#pragma unroll
    for (int t = 0; t < 9; ++t) {
      const int ly = (pwl >> 3) + (t / 3) - 1 + 3;   // [2,11]
      const int lx = (pwl & 7) + (t % 3) - 1 + 4;    // [3,12]
      const int pt = (ly << 4) | lx;
#pragma unroll
      for (int hf = 0; hf < 2; ++hf) {
        const int c8 = (hf << 2) | kgrp;
        bf16x8 bfr = *(const bf16x8*)&ldsx[(pt << 6) | ((c8 ^ (pt & 7)) << 3)];
        bf16x8 a0 = *(const bf16x8*)&owt[(((t << 5) | pl) << 6) | (c8 << 3)];
        bf16x8 a1 = *(const bf16x8*)&owt[(((t << 5) | 16 | pl) << 6) | (c8 << 3)];
        aoff0 = __builtin_amdgcn_mfma_f32_16x16x32_bf16(a0, bfr, aoff0, 0, 0, 0);
        aoff1 = __builtin_amdgcn_mfma_f32_16x16x32_bf16(a1, bfr, aoff1, 0, 0, 0);
      }
    }
    ow0 = aoff0[0] + ob[(kgrp << 2) + 0];
    ow1 = aoff0[1] + ob[(kgrp << 2) + 1];
    ow2 = aoff0[2] + ob[(kgrp << 2) + 2];
    ow3 = aoff0[3] + ob[(kgrp << 2) + 3];
    owA = aoff1[0] + ob[16];              // only meaningful on kgrp==0 lanes
    owB = aoff1[1] + ob[17];
  }

  // distribute: lane (kgrp,pl) needs (dy,dx) for taps k=0..8 of its pixel pwl;
  // offset o lives at lane ((o>>2)<<4)|pl, reg o&3. No barrier needed (intra-wave).
  float dyk[9], dxk[9];
#pragma unroll
  for (int k = 0; k < 8; ++k) {
    int src = ((k >> 1) << 4) | pl;
    dyk[k] = __shfl((k & 1) ? ow2 : ow0, src, 64);
    dxk[k] = __shfl((k & 1) ? ow3 : ow1, src, 64);
  }
  dyk[8] = __shfl(owA, pl, 64);
  dxk[8] = __shfl(owB, pl, 64);

  // ---- phase 2: tap loop, branch-free, no barriers ----
  f32x4 acc[4];
#pragma unroll
  for (int mt = 0; mt < 4; ++mt) acc[mt] = (f32x4){0.f, 0.f, 0.f, 0.f};

#pragma unroll
  for (int k = 0; k < 9; ++k) {
    // A-fragments for this tap (issued early; independent of sample chain)
    bf16x8 af[2][4];
#pragma unroll
    for (int hf = 0; hf < 2; ++hf)
#pragma unroll
      for (int mt = 0; mt < 4; ++mt)
        af[hf][mt] = *(const bf16x8*)&dwt[(k << 12) + (((mt << 4) | pl) << 6)
                                          + (hf << 5) + (kgrp << 3)];

    const float py = (float)(pyy + (k / 3) - 1) + dyk[k];
    const float px = (float)(pxx + (k % 3) - 1) + dxk[k];
    const float fy = floorf(py), fx = floorf(px);
    const int iy = (int)fy, ix = (int)fx;
    const float wy = py - fy, wx = px - fx;
    const float wy1 = 1.f - wy, wx1 = 1.f - wx;
    const bool ry0 = (unsigned)iy < (unsigned)H_;
    const bool ry1 = (unsigned)(iy + 1) < (unsigned)H_;
    const bool rx0 = (unsigned)ix < (unsigned)W_;
    const bool rx1 = (unsigned)(ix + 1) < (unsigned)W_;
    const float w00 = (ry0 & rx0) ? wy1 * wx1 : 0.f;
    const float w01 = (ry0 & rx1) ? wy1 * wx : 0.f;
    const float w10 = (ry1 & rx0) ? wy * wx1 : 0.f;
    const float w11 = (ry1 & rx1) ? wy * wx : 0.f;

    const int ly = iy - oy, lx = ix - ox;
    const int lyc = min(max(ly, 0), 13);
    const int lxc = min(max(lx, 0), 14);
    const bool oob = (ly != lyc) | (lx != lxc);   // needs |offset|>=2: ~never
    const int pt00 = (lyc << 4) | lxc;

    float s0[8], s1[8];
#pragma unroll
    for (int hf = 0; hf < 2; ++hf) {
      const int c8 = (hf << 2) | kgrp;
      float* s = hf ? s1 : s0;
      const unsigned short* l00 = &ldsx[(pt00 << 6) | ((c8 ^ (pt00 & 7)) << 3)];
      const unsigned short* l01 = &ldsx[((pt00 + 1) << 6) | ((c8 ^ ((pt00 + 1) & 7)) << 3)];
      const unsigned short* l10 = &ldsx[((pt00 + 16) << 6) | ((c8 ^ ((pt00 + 16) & 7)) << 3)];
      const unsigned short* l11 = &ldsx[((pt00 + 17) << 6) | ((c8 ^ ((pt00 + 17) & 7)) << 3)];
      u32x4 q00 = *(const u32x4*)l00;
      u32x4 q01 = *(const u32x4*)l01;
      u32x4 q10 = *(const u32x4*)l10;
      u32x4 q11 = *(const u32x4*)l11;
#pragma unroll
      for (int j = 0; j < 4; ++j) {
        float e = __uint_as_float(q00[j] << 16) * w00;
        e = fmaf(__uint_as_float(q01[j] << 16), w01, e);
        e = fmaf(__uint_as_float(q10[j] << 16), w10, e);
        e = fmaf(__uint_as_float(q11[j] << 16), w11, e);
        float o = __uint_as_float(q00[j] & 0xffff0000u) * w00;
        o = fmaf(__uint_as_float(q01[j] & 0xffff0000u), w01, o);
        o = fmaf(__uint_as_float(q10[j] & 0xffff0000u), w10, o);
        o = fmaf(__uint_as_float(q11[j] & 0xffff0000u), w11, o);
        s[2 * j] = e;
        s[2 * j + 1] = o;
      }
    }

    // cold repair: only if some lane's sample strayed out of the halo tile
    if (__builtin_expect(__ballot(oob) != 0ull, 0)) {
      if (oob) {
        int y0 = min(max(iy, 0), H_ - 1), x0 = min(max(ix, 0), W_ - 1);
        int y1 = min(max(iy + 1, 0), H_ - 1), x1 = min(max(ix + 1, 0), W_ - 1);
#pragma unroll
        for (int hf = 0; hf < 2; ++hf) {
          float* s = hf ? s1 : s0;
          const float* xp = x + (size_t)(b * CIN_ + (((hf << 2) | kgrp) << 3)) * (H_ * W_);
          for (int ci = 0; ci < 8; ++ci) {
            const float* xc = xp + ci * (H_ * W_);
            s[ci] = xc[y0 * W_ + x0] * w00 + xc[y0 * W_ + x1] * w01 +
                    xc[y1 * W_ + x0] * w10 + xc[y1 * W_ + x1] * w11;
          }
        }
      }
    }

    union { bf16x8 v; u32x4 w; } bf0, bf1;
#pragma unroll
    for (int j = 0; j < 4; ++j) {
      bf0.w[j] = cvt_pk_bf16(s0[2 * j], s0[2 * j + 1]);
      bf1.w[j] = cvt_pk_bf16(s1[2 * j], s1[2 * j + 1]);
    }
#pragma unroll
    for (int mt = 0; mt < 4; ++mt)
      acc[mt] = __builtin_amdgcn_mfma_f32_16x16x32_bf16(af[0][mt], bf0.v, acc[mt], 0, 0, 0);
#pragma unroll
    for (int mt = 0; mt < 4; ++mt)
      acc[mt] = __builtin_amdgcn_mfma_f32_16x16x32_bf16(af[1][mt], bf1.v, acc[mt], 0, 0, 0);
  }

  // ---- epilogue: D col=lane&15 (pixel), row=(lane>>4)*4+j (cout in M-tile) ----
#pragma unroll
  for (int mt = 0; mt < 4; ++mt) {
#pragma unroll
    for (int j = 0; j < 4; ++j) {
      int o = (mt << 4) | (kgrp << 2) | j;
      float v = acc[mt][j] + db[o];
      out[((b * COUT_ + o) * H_ + pyy) * W_ + pxx] = v > 0.f ? v : 0.f;
    }
  }
}

extern "C" void kernel_launch(void* const* d_in, const int* in_sizes, int n_in,
                              void* d_out, int out_size, void* d_ws, size_t ws_size,
                              hipStream_t stream) {
  const float* x  = (const float*)d_in[0];
  const float* ow = (const float*)d_in[1];
  const float* ob = (const float*)d_in[2];
  const float* dw = (const float*)d_in[3];
  const float* db = (const float*)d_in[4];
  float* out = (float*)d_out;

  unsigned short* dwt = (unsigned short*)d_ws;                    // 36864 bf16
  unsigned short* owt = (unsigned short*)((char*)d_ws + 73728);   // 18432 bf16

  hipLaunchKernelGGL(prep_w, dim3(216), dim3(256), 0, stream, dw, ow, dwt, owt);
  hipLaunchKernelGGL(deform_main, dim3(2048), dim3(256), 0, stream,
                     x, owt, ob, dwt, db, out);
}